// Round 4
// baseline (32.865 us; speedup 1.0000x reference)
//
#include <hip/hip_runtime.h>

#define BB 2048          // batches
#define TT 4096          // timesteps
#define LN2 0.69314718055994530942f

// ---------------------------------------------------------------------------
// One-kernel CRF fold (round 4).
//   * block = one batch row (256 threads x 16 timesteps).
//   * per-thread 16-step exp-domain chunk product; 4 int4 tag loads issued
//     FIRST, then 12 float4 logit loads, sched_barrier -> full 16KB clause in
//     flight. Tags packed to ONE reg (2 bits each) right after their arrival
//     (waitcnt vmcnt(12): logits still streaming) -> frees 16 VGPRs.
//   * ordered shfl_down fold: lane i merges [i,i+m) x [i+m,i+2m), self is
//     always the LEFT operand -> zero cndmask (vs 22/round for xor variant).
//     Only lane 0's record is valid at the end - the only one used.
//     Merge tree for lane 0 identical to the old butterfly -> bit-exact.
//   * alpha0 (v = exp(logits[b,0,:])) re-read by tid 0 at the END (L1-hit)
//     instead of being carried in registers through the whole kernel.
//   * launch_bounds(256,5): VGPR cap 102; estimated live-set ~80.
// Traffic: read 134 MB, write 8 KB -> 21.3 us floor at 6.3 TB/s.
// ---------------------------------------------------------------------------
__global__ __launch_bounds__(256, 5) void crf_pass1(
    const float* __restrict__ logits, const float* __restrict__ trans,
    const int* __restrict__ tags, float* __restrict__ ws)
{
    __shared__ float sTrans[9];
    __shared__ float sTrExp[9];
    __shared__ float sRec[3][12];      // records of waves 1..3
    const int tid = threadIdx.x;
    if (tid < 9) {
        float tv = trans[tid];
        sTrans[tid] = tv;
        sTrExp[tid] = __expf(tv);
    }
    __syncthreads();

    const int b = blockIdx.x;
    const int c = tid;                 // chunk index = thread index

    const int4*   tp = (const int4*)(tags + (size_t)b * TT + (size_t)c * 16);
    const float4* lp = (const float4*)(logits + ((size_t)b * TT + (size_t)c * 16) * 3);

    // ---- issue the ENTIRE clause: tags first, then logits ----
    int4 Tq[4];
#pragma unroll
    for (int i = 0; i < 4; ++i) Tq[i] = tp[i];
    float Lf[48];
#pragma unroll
    for (int i = 0; i < 12; ++i) {
        float4 t = lp[i];
        Lf[4*i+0] = t.x; Lf[4*i+1] = t.y; Lf[4*i+2] = t.z; Lf[4*i+3] = t.w;
    }
    __builtin_amdgcn_sched_barrier(0);   // all 16 loads issued before any use

    // pack 16 tags (values 0..2) into one reg; waits only on the tag loads
    unsigned pk = 0;
#pragma unroll
    for (int i = 0; i < 4; ++i) {
        pk |= ((unsigned)Tq[i].x << (8*i))     | ((unsigned)Tq[i].y << (8*i+2))
            | ((unsigned)Tq[i].z << (8*i+4))   | ((unsigned)Tq[i].w << (8*i+6));
    }

    float t00 = sTrExp[0], t01 = sTrExp[1], t02 = sTrExp[2];
    float t10 = sTrExp[3], t11 = sTrExp[4], t12 = sTrExp[5];
    float t20 = sTrExp[6], t21 = sTrExp[7], t22 = sTrExp[8];

    float a00 = 1.f, a01 = 0.f, a02 = 0.f;
    float a10 = 0.f, a11 = 1.f, a12 = 0.f;
    float a20 = 0.f, a21 = 0.f, a22 = 1.f;
    int   se = 0;
    float score = 0.f;
    unsigned long long acc = 0ull;     // 9 x 7-bit transition-pair counters
    int prev = 0;

#define MATSTEP(e0_, e1_, e2_) do {                                     \
    float x0 = __expf(e0_), x1 = __expf(e1_), x2 = __expf(e2_);         \
    float b0 = (a00*t00 + a01*t10 + a02*t20) * x0;                      \
    float b1 = (a00*t01 + a01*t11 + a02*t21) * x1;                      \
    float b2 = (a00*t02 + a01*t12 + a02*t22) * x2;                      \
    float b3 = (a10*t00 + a11*t10 + a12*t20) * x0;                      \
    float b4 = (a10*t01 + a11*t11 + a12*t21) * x1;                      \
    float b5 = (a10*t02 + a11*t12 + a12*t22) * x2;                      \
    float b6 = (a20*t00 + a21*t10 + a22*t20) * x0;                      \
    float b7 = (a20*t01 + a21*t11 + a22*t21) * x1;                      \
    float b8 = (a20*t02 + a21*t12 + a22*t22) * x2;                      \
    a00=b0; a01=b1; a02=b2; a10=b3; a11=b4; a12=b5; a20=b6; a21=b7; a22=b8; \
} while (0)

#define RENORM do {                                                     \
    float m_ = fmaxf(fmaxf(fmaxf(a00, a01), fmaxf(a02, a10)),           \
                     fmaxf(fmaxf(a11, a12), fmaxf(fmaxf(a20, a21), a22))); \
    int ef_ = (int)(__float_as_uint(m_) >> 23);                         \
    float scf_ = __uint_as_float((unsigned)(254 - ef_) << 23);          \
    se += ef_ - 127;                                                    \
    a00 *= scf_; a01 *= scf_; a02 *= scf_;                              \
    a10 *= scf_; a11 *= scf_; a12 *= scf_;                              \
    a20 *= scf_; a21 *= scf_; a22 *= scf_;                              \
} while (0)

    // ---- 16 steps ----
#pragma unroll
    for (int s = 0; s < 16; ++s) {
        float e0 = Lf[3*s+0], e1 = Lf[3*s+1], e2 = Lf[3*s+2];
        int tg = (int)((pk >> (2*s)) & 3u);
        if (s == 0) {
            // chunk 0: t=0 is alpha0 (no transition step, emission handled
            // via v at the end) -> skip MATSTEP only for c==0
            if (c != 0) MATSTEP(e0, e1, e2);
        } else {
            MATSTEP(e0, e1, e2);
            acc += 1ull << (7 * (prev * 3 + tg));   // pure-VALU transition count
        }
        score += (tg == 0) ? e0 : ((tg == 1) ? e1 : e2);
        prev = tg;
        if ((s & 7) == 7) RENORM;
    }

    int firstTag = (int)(pk & 3u);

    // fold transition-pair counts into score (max count 15 < 127)
#pragma unroll
    for (int p = 0; p < 9; ++p)
        score += (float)((int)((acc >> (7 * p)) & 127ull)) * sTrans[p];

    // ---- ordered shfl_down fold of 64 chunk records (lane 0 ends valid) ----
#pragma unroll
    for (int m = 1; m < 64; m <<= 1) {
        float o00 = __shfl_down(a00, m, 64), o01 = __shfl_down(a01, m, 64), o02 = __shfl_down(a02, m, 64);
        float o10 = __shfl_down(a10, m, 64), o11 = __shfl_down(a11, m, 64), o12 = __shfl_down(a12, m, 64);
        float o20 = __shfl_down(a20, m, 64), o21 = __shfl_down(a21, m, 64), o22 = __shfl_down(a22, m, 64);
        int   ose = __shfl_down(se, m, 64);
        float osc = __shfl_down(score, m, 64);
        int   ofi = __shfl_down(firstTag, m, 64);   // right block's first tag
        int   opv = __shfl_down(prev, m, 64);       // right block's last tag

        // C = self(left) x other(right); no selects
        float c00 = a00*o00 + a01*o10 + a02*o20;
        float c01 = a00*o01 + a01*o11 + a02*o21;
        float c02 = a00*o02 + a01*o12 + a02*o22;
        float c10 = a10*o00 + a11*o10 + a12*o20;
        float c11 = a10*o01 + a11*o11 + a12*o21;
        float c12 = a10*o02 + a11*o12 + a12*o22;
        float c20 = a20*o00 + a21*o10 + a22*o20;
        float c21 = a20*o01 + a21*o11 + a22*o21;
        float c22 = a20*o02 + a21*o12 + a22*o22;

        score = score + osc + sTrans[prev * 3 + ofi];  // seam transition
        prev = opv;
        se += ose;

        a00=c00; a01=c01; a02=c02; a10=c10; a11=c11; a12=c12; a20=c20; a21=c21; a22=c22;
        RENORM;
    }

    // ---- cross-wave fold (waves are time-ordered) ----
    const int lane = tid & 63;
    const int wid  = tid >> 6;
    if (lane == 0 && wid > 0) {
        sRec[wid-1][0] = a00; sRec[wid-1][1] = a01; sRec[wid-1][2] = a02;
        sRec[wid-1][3] = a10; sRec[wid-1][4] = a11; sRec[wid-1][5] = a12;
        sRec[wid-1][6] = a20; sRec[wid-1][7] = a21; sRec[wid-1][8] = a22;
        sRec[wid-1][9]  = __int_as_float(se);
        sRec[wid-1][10] = score;
        sRec[wid-1][11] = __int_as_float(firstTag | (prev << 8));
    }
    __syncthreads();
    if (tid == 0) {
#pragma unroll
        for (int k = 0; k < 3; ++k) {
            float m00 = sRec[k][0], m01 = sRec[k][1], m02 = sRec[k][2];
            float m10 = sRec[k][3], m11 = sRec[k][4], m12 = sRec[k][5];
            float m20 = sRec[k][6], m21 = sRec[k][7], m22 = sRec[k][8];
            int   shm = __float_as_int(sRec[k][9]);
            float scm = sRec[k][10];
            int   pkm = __float_as_int(sRec[k][11]);

            float c00 = a00*m00 + a01*m10 + a02*m20;
            float c01 = a00*m01 + a01*m11 + a02*m21;
            float c02 = a00*m02 + a01*m12 + a02*m22;
            float c10 = a10*m00 + a11*m10 + a12*m20;
            float c11 = a10*m01 + a11*m11 + a12*m21;
            float c12 = a10*m02 + a11*m12 + a12*m22;
            float c20 = a20*m00 + a21*m10 + a22*m20;
            float c21 = a20*m01 + a21*m11 + a22*m21;
            float c22 = a20*m02 + a21*m12 + a22*m22;

            score += scm + sTrans[prev * 3 + (pkm & 255)];
            prev = pkm >> 8;
            se += shm;
            a00=c00; a01=c01; a02=c02; a10=c10; a11=c11; a12=c12; a20=c20; a21=c21; a22=c22;
            RENORM;
        }
        // alpha0 re-read (L1-hit: same line thread 0's clause already fetched)
        const float* lb = logits + (size_t)b * TT * 3;
        float v0 = __expf(lb[0]);
        float v1 = __expf(lb[1]);
        float v2 = __expf(lb[2]);
        // alpha_T = v . P  (row-vector times total product), value * 2^se
        float n0 = v0*a00 + v1*a10 + v2*a20;
        float n1 = v0*a01 + v1*a11 + v2*a21;
        float n2 = v0*a02 + v1*a12 + v2*a22;
        float logz = logf(n0 + n1 + n2) + (float)se * LN2;
        ws[b] = logz - score;          // per-batch nll
    }

#undef MATSTEP
#undef RENORM
}

// ---------------------------------------------------------------------------
// Final reduction: one block sums the 2048 per-batch nll values.
// ---------------------------------------------------------------------------
__global__ __launch_bounds__(256) void crf_reduce(
    const float* __restrict__ ws, float* __restrict__ out)
{
    int tid = threadIdx.x;
    float s = 0.f;
#pragma unroll
    for (int k = 0; k < BB / 256; ++k) s += ws[k * 256 + tid];
    for (int off = 32; off > 0; off >>= 1) s += __shfl_down(s, off, 64);
    __shared__ float sP[4];
    if ((tid & 63) == 0) sP[tid >> 6] = s;
    __syncthreads();
    if (tid == 0) out[0] = sP[0] + sP[1] + sP[2] + sP[3];
}

extern "C" void kernel_launch(void* const* d_in, const int* in_sizes, int n_in,
                              void* d_out, int out_size, void* d_ws, size_t ws_size,
                              hipStream_t stream) {
    const float* logits = (const float*)d_in[0];
    const float* trans  = (const float*)d_in[1];
    const int*   tags   = (const int*)d_in[2];
    float* out = (float*)d_out;
    float* ws  = (float*)d_ws;

    crf_pass1<<<dim3(BB), dim3(256), 0, stream>>>(logits, trans, tags, ws);
    crf_reduce<<<dim3(1), dim3(256), 0, stream>>>(ws, out);
}